// Round 1
// baseline (597.855 us; speedup 1.0000x reference)
//
#include <hip/hip_runtime.h>

#define TN 16000
#define NT 640

__device__ __forceinline__ float2 cmulf(float2 a, float2 b){
  return make_float2(a.x*b.x - a.y*b.y, a.x*b.y + a.y*b.x);
}

// radix order {5,5,5,2,2,2,2,2,2,2}; DIF output position <-> frequency maps
__device__ __forceinline__ int pos2freq(int p){
  int u0 = p / 3200; int r0 = p - u0*3200;
  int u1 = r0 / 640; int r1 = r0 - u1*640;
  int u2 = r1 / 128; int p2 = r1 - u2*128;
  int q  = (int)(__brev((unsigned)p2) >> 25);
  return u0 + 5*u1 + 25*u2 + 125*q;
}
__device__ __forceinline__ int freq2pos(int k){
  int u0 = k % 5; int t = k / 5;
  int u1 = t % 5; t /= 5;
  int u2 = t % 5; int q = t / 5;
  int p2 = (int)(__brev((unsigned)q) >> 25);
  return u0*3200 + u1*640 + u2*128 + p2;
}

template<bool INV>
__device__ __forceinline__ void dft5(const float2* y, float2* z){
  const float CR[5] = {1.f, 0.30901699437494742f, -0.80901699437494745f,
                       -0.80901699437494745f, 0.30901699437494742f};
  const float CI[5] = {0.f, -0.95105651629515357f, -0.58778525229247313f,
                       0.58778525229247313f, 0.95105651629515357f};
#pragma unroll
  for (int u=0;u<5;u++){
    float zr=0.f, zi=0.f;
#pragma unroll
    for (int t=0;t<5;t++){
      const int m = (t*u)%5;
      const float wr = CR[m];
      const float wi = INV ? -CI[m] : CI[m];
      zr += y[t].x*wr - y[t].y*wi;
      zi += y[t].x*wi + y[t].y*wr;
    }
    z[u] = make_float2(zr, zi);
  }
}

template<int L, bool INV>
__device__ void stage5(float2* buf, int tid){
  const int M = L/5;
  for (int f = tid; f < TN/5; f += NT){
    const int b = f / M;
    const int j = f - b*M;
    float2* p = buf + b*L + j;
    float2 v[5], w[5];
#pragma unroll
    for (int t=0;t<5;t++) v[t] = p[t*M];
    const float ang = (INV ? 6.28318530717958647692f : -6.28318530717958647692f)
                      * ((float)j / (float)L);
    float sn, cs; __sincosf(ang, &sn, &cs);
    const float2 w1 = make_float2(cs, sn);
    const float2 w2 = cmulf(w1,w1);
    const float2 w3 = cmulf(w2,w1);
    const float2 w4 = cmulf(w2,w2);
    if (INV){
      v[1]=cmulf(v[1],w1); v[2]=cmulf(v[2],w2); v[3]=cmulf(v[3],w3); v[4]=cmulf(v[4],w4);
      dft5<true>(v, w);
    } else {
      dft5<false>(v, w);
      w[1]=cmulf(w[1],w1); w[2]=cmulf(w[2],w2); w[3]=cmulf(w[3],w3); w[4]=cmulf(w[4],w4);
    }
#pragma unroll
    for (int u=0;u<5;u++) p[u*M] = w[u];
  }
}

template<int L, bool INV>
__device__ void stage2(float2* buf, int tid){
  const int M = L/2;
  for (int f = tid; f < TN/2; f += NT){
    const int b = f / M;
    const int j = f - b*M;
    float2* p = buf + b*L + j;
    float2 a0 = p[0], a1 = p[M];
    if (INV){
      if (M > 1){
        const float ang = 6.28318530717958647692f * ((float)j / (float)L);
        float sn, cs; __sincosf(ang, &sn, &cs);
        a1 = cmulf(a1, make_float2(cs, sn));
      }
      p[0] = make_float2(a0.x+a1.x, a0.y+a1.y);
      p[M] = make_float2(a0.x-a1.x, a0.y-a1.y);
    } else {
      float2 s = make_float2(a0.x+a1.x, a0.y+a1.y);
      float2 d = make_float2(a0.x-a1.x, a0.y-a1.y);
      if (M > 1){
        const float ang = -6.28318530717958647692f * ((float)j / (float)L);
        float sn, cs; __sincosf(ang, &sn, &cs);
        d = cmulf(d, make_float2(cs, sn));
      }
      p[0] = s; p[M] = d;
    }
  }
}

__device__ void fft_fwd(float2* buf, int tid){
  stage5<16000,false>(buf,tid); __syncthreads();
  stage5<3200,false>(buf,tid);  __syncthreads();
  stage5<640,false>(buf,tid);   __syncthreads();
  stage2<128,false>(buf,tid);   __syncthreads();
  stage2<64,false>(buf,tid);    __syncthreads();
  stage2<32,false>(buf,tid);    __syncthreads();
  stage2<16,false>(buf,tid);    __syncthreads();
  stage2<8,false>(buf,tid);     __syncthreads();
  stage2<4,false>(buf,tid);     __syncthreads();
  stage2<2,false>(buf,tid);     __syncthreads();
}
__device__ void fft_inv(float2* buf, int tid){
  stage2<2,true>(buf,tid);     __syncthreads();
  stage2<4,true>(buf,tid);     __syncthreads();
  stage2<8,true>(buf,tid);     __syncthreads();
  stage2<16,true>(buf,tid);    __syncthreads();
  stage2<32,true>(buf,tid);    __syncthreads();
  stage2<64,true>(buf,tid);    __syncthreads();
  stage2<128,true>(buf,tid);   __syncthreads();
  stage5<640,true>(buf,tid);   __syncthreads();
  stage5<3200,true>(buf,tid);  __syncthreads();
  stage5<16000,true>(buf,tid); __syncthreads();
}

__device__ __forceinline__ float norm_val(float s){
  // eval-mode normalization; 1/(1+1e-8) == 1 in fp32
  const float v = s;
  const float lt = log1pf(fabsf(v)*1.0e5f)*1.0e-5f;
  return 0.7f*v + 0.3f*copysignf(lt, v);
}

// buf holds a spectrum in digit-reversed order; fold with PHI into 125 bins,
// 125-point IDFT (x 1/T), normalize and store one 125-sample output row.
__device__ void lowpass_fold_store(const float2* buf, float2* fb, int tid, float* out_row){
  if (tid < 125){
    float2 acc = make_float2(0.f, 0.f);
#pragma unroll
    for (int jj=0; jj<10; ++jj){
      const int j = (jj<5) ? jj : (jj+118);            // j in {0..4, 123..127}
      const int k = tid + 125*j;
      const float om = (float)k * (1.0f/16000.0f);
      const float d0 = om, d1 = om - 1.0f;
      // -1/(2*sig_phi^2) = -51200 exactly (sig_phi = 0.4/128)
      const float w = expf(-51200.0f*d0*d0) + expf(-51200.0f*d1*d1);
      const float2 z = buf[freq2pos(k)];
      acc.x += w*z.x; acc.y += w*z.y;
    }
    fb[tid] = acc;
  }
  __syncthreads();
  if (tid < 125){
    float s = 0.f;
    for (int m=0;m<125;m++){
      const int mo = (m*tid) % 125;
      const float ang = (float)mo * (6.28318530717958647692f/125.0f);
      float sn, cs; __sincosf(ang, &sn, &cs);
      const float2 y = fb[m];
      s += y.x*cs - y.y*sn;
    }
    out_row[tid] = norm_val(s * (1.0f/16000.0f));
  }
}

// ---------------- kernel 1: window + FFT(x) + S0 ----------------
__global__ __launch_bounds__(NT) void k_fftx(const float* __restrict__ x,
                                             float2* __restrict__ Xrev,
                                             float* __restrict__ out){
  __shared__ float2 buf[TN];
  __shared__ float2 fb[125];
  const int tid = threadIdx.x;
  const int b = blockIdx.x;
  const float* xb = x + b*TN;
  for (int n = tid; n < TN; n += NT){
    float c = __cosf((float)n * (6.28318530717958647692f/16000.0f));
    float wn = 0.08f + 0.46f*(1.0f - c);
    buf[n] = make_float2(xb[n]*wn, 0.f);
  }
  __syncthreads();
  fft_fwd(buf, tid);
  float2* Xb = Xrev + b*TN;
  for (int p = tid; p < TN; p += NT) Xb[p] = buf[p];
  lowpass_fold_store(buf, fb, tid, out + (size_t)b*337*125);
}

// ---------------- kernel 2: order 1 (ifft(X*psi1) -> |.| -> fft -> S1 + U1h) ----------------
__global__ __launch_bounds__(NT) void k_order1(const float2* __restrict__ Xrev,
                                               float2* __restrict__ U1h,
                                               float* __restrict__ out){
  __shared__ float2 buf[TN];
  __shared__ float2 fb[125];
  const int tid = threadIdx.x;
  const int b  = blockIdx.x / 84;
  const int p1 = blockIdx.x % 84;
  const float xi = 0.5f * exp2f(-(float)(p1+1) * (1.0f/12.0f));
  const float sg = xi * 0.11892618871859045f;           // (2^(1/12)-1)*2
  const float ninv2s2 = -1.0f/(2.0f*sg*sg);
  const float2* Xb = Xrev + (size_t)b*TN;
  for (int p = tid; p < TN; p += NT){
    const int k = pos2freq(p);
    const float d = (float)k*(1.0f/16000.0f) - xi;
    const float g = expf(ninv2s2*d*d);
    const float2 v = Xb[p];
    buf[p] = make_float2(v.x*g, v.y*g);
  }
  __syncthreads();
  fft_inv(buf, tid);
  for (int n = tid; n < TN; n += NT){
    const float2 v = buf[n];
    buf[n] = make_float2(sqrtf(v.x*v.x + v.y*v.y) * (1.0f/16000.0f), 0.f);
  }
  __syncthreads();
  fft_fwd(buf, tid);
  float2* Ub = U1h + (size_t)(b*84 + p1)*TN;
  for (int p = tid; p < TN; p += NT) Ub[p] = buf[p];
  lowpass_fold_store(buf, fb, tid, out + ((size_t)b*337 + 1 + p1)*125);
}

// ---------------- kernel 3: order 2 (ifft(U1h*psi2) -> |.| -> conv phi -> S2) ----------------
__global__ __launch_bounds__(NT) void k_order2(const float2* __restrict__ U1h,
                                               float* __restrict__ out){
  __shared__ float2 buf[TN];
  __shared__ float hb[641];
  __shared__ float part[625];
  const int tid = threadIdx.x;
  const int b = blockIdx.x / 252;
  const int q = blockIdx.x % 252;
  // decode path q -> (p1, j2): iterate octave a = j1
  int a = 0, rem = q;
  while (rem >= 12*(6-a)) { rem -= 12*(6-a); ++a; }
  const int nj = 6 - a;
  const int p1 = 12*a + rem/nj;
  const int j2 = a + 1 + rem % nj;
  const float xi = 0.5f * exp2f(-(float)(j2+1));
  const float sg = 0.5f*xi;
  const float ninv2s2 = -1.0f/(2.0f*sg*sg);
  // time-domain lowpass kernel h[d] = sqrt(2pi)*sig_phi * exp(-2*pi^2*sig_phi^2*d^2)
  for (int i = tid; i < 641; i += NT){
    const float d = (float)(i-320);
    hb[i] = 0.0078332134f * expf(-1.9276571e-4f * d*d);
  }
  const float2* Zb = U1h + (size_t)(b*84 + p1)*TN;
  for (int p = tid; p < TN; p += NT){
    const int k = pos2freq(p);
    const float d = (float)k*(1.0f/16000.0f) - xi;
    const float g = expf(ninv2s2*d*d);
    const float2 v = Zb[p];
    buf[p] = make_float2(v.x*g, v.y*g);
  }
  __syncthreads();
  fft_inv(buf, tid);
  for (int n = tid; n < TN; n += NT){
    const float2 v = buf[n];
    buf[n] = make_float2(sqrtf(v.x*v.x + v.y*v.y)*(1.0f/16000.0f), 0.f);
  }
  __syncthreads();
  // circular conv, 5 threads per output sample (125 outputs)
  if (tid < 625){
    const int o = tid / 5, g = tid % 5;
    const int t0 = 128*o;
    float acc = 0.f;
    for (int i = g; i < 641; i += 5){
      const int d = i - 320;
      int idx = t0 - d;
      idx += (idx < 0) ? 16000 : 0;
      idx -= (idx >= 16000) ? 16000 : 0;
      acc += hb[i]*buf[idx].x;
    }
    part[tid] = acc;
  }
  __syncthreads();
  if (tid < 125){
    const float s = part[5*tid] + part[5*tid+1] + part[5*tid+2]
                  + part[5*tid+3] + part[5*tid+4];
    out[((size_t)b*337 + 85 + q)*125 + tid] = norm_val(s);
  }
}

extern "C" void kernel_launch(void* const* d_in, const int* in_sizes, int n_in,
                              void* d_out, int out_size, void* d_ws, size_t ws_size,
                              hipStream_t stream){
  (void)in_sizes; (void)n_in; (void)out_size; (void)ws_size;
  const float* x = (const float*)d_in[0];
  float* out = (float*)d_out;
  float2* Xrev = (float2*)d_ws;                                        // 8*16000 cplx = 1.0 MB
  float2* U1h  = (float2*)((char*)d_ws + (size_t)8*TN*sizeof(float2)); // 672*16000 cplx = 86 MB
  k_fftx  <<<8,     NT, 0, stream>>>(x, Xrev, out);
  k_order1<<<8*84,  NT, 0, stream>>>(Xrev, U1h, out);
  k_order2<<<8*252, NT, 0, stream>>>(U1h, out);
}

// Round 2
// 323.463 us; speedup vs baseline: 1.8483x; 1.8483x over previous
//
#include <hip/hip_runtime.h>

#define TN 16000
#define NT 640

constexpr int ilog2c(int x){ return (x<=1)?0:1+ilog2c(x/2); }

__device__ __forceinline__ float2 cmulf(float2 a, float2 b){
  return make_float2(a.x*b.x - a.y*b.y, a.x*b.y + a.y*b.x);
}

// radix order {5,5,5,2,...}; DIF output position <-> frequency maps, N = 125*2^C
__device__ __forceinline__ int pos2freq(int p){
  int u0 = p / 3200; int r0 = p - u0*3200;
  int u1 = r0 / 640; int r1 = r0 - u1*640;
  int u2 = r1 / 128; int p2 = r1 - u2*128;
  int q  = (int)(__brev((unsigned)p2) >> 25);
  return u0 + 5*u1 + 25*u2 + 125*q;
}
template<int N>
__device__ __forceinline__ int freq2pos_g(int k){
  constexpr int C = ilog2c(N/125);
  int u0 = k % 5; int t = k / 5;
  int u1 = t % 5; t /= 5;
  int u2 = t % 5; int q = t / 5;
  int p2 = (C==0) ? q : (int)(__brev((unsigned)q) >> (32-C));
  return u0*(N/5) + u1*(N/25) + u2*(N/125) + p2;
}

template<bool INV>
__device__ __forceinline__ void dft5(const float2* y, float2* z){
  const float CR[5] = {1.f, 0.30901699437494742f, -0.80901699437494745f,
                       -0.80901699437494745f, 0.30901699437494742f};
  const float CI[5] = {0.f, -0.95105651629515357f, -0.58778525229247313f,
                       0.58778525229247313f, 0.95105651629515357f};
#pragma unroll
  for (int u=0;u<5;u++){
    float zr=0.f, zi=0.f;
#pragma unroll
    for (int t=0;t<5;t++){
      const int m = (t*u)%5;
      const float wr = CR[m];
      const float wi = INV ? -CI[m] : CI[m];
      zr += y[t].x*wr - y[t].y*wi;
      zi += y[t].x*wi + y[t].y*wr;
    }
    z[u] = make_float2(zr, zi);
  }
}

template<int N, int L, bool INV>
__device__ void stage5(float2* buf, int tid, int nt){
  const int M = L/5;
  for (int f = tid; f < N/5; f += nt){
    const int b = f / M;
    const int j = f - b*M;
    float2* p = buf + b*L + j;
    float2 v[5], w[5];
#pragma unroll
    for (int t=0;t<5;t++) v[t] = p[t*M];
    const float ang = (INV ? 6.28318530717958647692f : -6.28318530717958647692f)
                      * ((float)j / (float)L);
    float sn, cs; __sincosf(ang, &sn, &cs);
    const float2 w1 = make_float2(cs, sn);
    const float2 w2 = cmulf(w1,w1);
    const float2 w3 = cmulf(w2,w1);
    const float2 w4 = cmulf(w2,w2);
    if (INV){
      v[1]=cmulf(v[1],w1); v[2]=cmulf(v[2],w2); v[3]=cmulf(v[3],w3); v[4]=cmulf(v[4],w4);
      dft5<true>(v, w);
    } else {
      dft5<false>(v, w);
      w[1]=cmulf(w[1],w1); w[2]=cmulf(w[2],w2); w[3]=cmulf(w[3],w3); w[4]=cmulf(w[4],w4);
    }
#pragma unroll
    for (int u=0;u<5;u++) p[u*M] = w[u];
  }
}

template<int N, int L, bool INV>
__device__ void stage2(float2* buf, int tid, int nt){
  const int M = L/2;
  for (int f = tid; f < N/2; f += nt){
    const int b = f / M;
    const int j = f - b*M;
    float2* p = buf + b*L + j;
    float2 a0 = p[0], a1 = p[M];
    if (INV){
      if (M > 1){
        const float ang = 6.28318530717958647692f * ((float)j / (float)L);
        float sn, cs; __sincosf(ang, &sn, &cs);
        a1 = cmulf(a1, make_float2(cs, sn));
      }
      p[0] = make_float2(a0.x+a1.x, a0.y+a1.y);
      p[M] = make_float2(a0.x-a1.x, a0.y-a1.y);
    } else {
      float2 s = make_float2(a0.x+a1.x, a0.y+a1.y);
      float2 d = make_float2(a0.x-a1.x, a0.y-a1.y);
      if (M > 1){
        const float ang = -6.28318530717958647692f * ((float)j / (float)L);
        float sn, cs; __sincosf(ang, &sn, &cs);
        d = cmulf(d, make_float2(cs, sn));
      }
      p[0] = s; p[M] = d;
    }
  }
}

template<int N, int L>
__device__ __forceinline__ void fwd_r2_chain(float2* buf, int tid, int nt){
  if constexpr (L >= 2){
    stage2<N, L, false>(buf, tid, nt);
    __syncthreads();
    fwd_r2_chain<N, L/2>(buf, tid, nt);
  }
}
template<int N>
__device__ void fft_fwd_g(float2* buf, int tid, int nt){
  stage5<N, N,    false>(buf, tid, nt); __syncthreads();
  stage5<N, N/5,  false>(buf, tid, nt); __syncthreads();
  stage5<N, N/25, false>(buf, tid, nt); __syncthreads();
  fwd_r2_chain<N, N/125>(buf, tid, nt);
}
template<int N, int L>
__device__ __forceinline__ void inv_r2_chain(float2* buf, int tid, int nt){
  if constexpr (L <= N/125){
    stage2<N, L, true>(buf, tid, nt);
    __syncthreads();
    inv_r2_chain<N, L*2>(buf, tid, nt);
  }
}
template<int N>
__device__ void fft_inv_g(float2* buf, int tid, int nt){
  inv_r2_chain<N, 2>(buf, tid, nt);
  stage5<N, N/25, true>(buf, tid, nt); __syncthreads();
  stage5<N, N/5,  true>(buf, tid, nt); __syncthreads();
  stage5<N, N,    true>(buf, tid, nt); __syncthreads();
}

__device__ __forceinline__ float norm_val(float s){
  const float v = s;
  const float lt = log1pf(fabsf(v)*1.0e5f)*1.0e-5f;
  return 0.7f*v + 0.3f*copysignf(lt, v);
}

// buf holds a 16000-pt spectrum in digit-reversed order; fold with PHI into
// 125 bins, 125-point IDFT (x 1/T), normalize, store one output row.
__device__ void lowpass_fold_store(const float2* buf, float2* fb, int tid, float* out_row){
  if (tid < 125){
    float2 acc = make_float2(0.f, 0.f);
#pragma unroll
    for (int jj=0; jj<10; ++jj){
      const int j = (jj<5) ? jj : (jj+118);
      const int k = tid + 125*j;
      const float om = (float)k * (1.0f/16000.0f);
      const float d0 = om, d1 = om - 1.0f;
      const float w = expf(-51200.0f*d0*d0) + expf(-51200.0f*d1*d1);
      const float2 z = buf[freq2pos_g<16000>(k)];
      acc.x += w*z.x; acc.y += w*z.y;
    }
    fb[tid] = acc;
  }
  __syncthreads();
  if (tid < 125){
    float s = 0.f;
    for (int m=0;m<125;m++){
      const int mo = (m*tid) % 125;
      const float ang = (float)mo * (6.28318530717958647692f/125.0f);
      float sn, cs; __sincosf(ang, &sn, &cs);
      const float2 y = fb[m];
      s += y.x*cs - y.y*sn;
    }
    out_row[tid] = norm_val(s * (1.0f/16000.0f));
  }
}

// ---------------- kernel 1: window + FFT(x) + S0 ----------------
__global__ __launch_bounds__(NT) void k_fftx(const float* __restrict__ x,
                                             float2* __restrict__ Xrev,
                                             float* __restrict__ out){
  __shared__ float2 buf[TN];
  __shared__ float2 fb[125];
  const int tid = threadIdx.x;
  const int b = blockIdx.x;
  const float* xb = x + b*TN;
  for (int n = tid; n < TN; n += NT){
    float c = __cosf((float)n * (6.28318530717958647692f/16000.0f));
    float wn = 0.08f + 0.46f*(1.0f - c);
    buf[n] = make_float2(xb[n]*wn, 0.f);
  }
  __syncthreads();
  fft_fwd_g<16000>(buf, tid, NT);
  float2* Xb = Xrev + b*TN;
  for (int p = tid; p < TN; p += NT) Xb[p] = buf[p];
  lowpass_fold_store(buf, fb, tid, out + (size_t)b*337*125);
}

// ---------------- kernel 2: order 1 ----------------
// U1h stored in NATURAL order, prefix only (per-octave length), stride 8000.
__global__ __launch_bounds__(NT) void k_order1(const float2* __restrict__ Xrev,
                                               float2* __restrict__ U1h,
                                               float* __restrict__ out){
  __shared__ float2 buf[TN];
  __shared__ float2 fb[125];
  const int tid = threadIdx.x;
  const int b  = blockIdx.x / 84;
  const int p1 = blockIdx.x % 84;
  const float xi = 0.5f * exp2f(-(float)(p1+1) * (1.0f/12.0f));
  const float sg = xi * 0.11892618871859045f;
  const float ninv2s2 = -1.0f/(2.0f*sg*sg);
  const float2* Xb = Xrev + (size_t)b*TN;
  for (int p = tid; p < TN; p += NT){
    const int k = pos2freq(p);
    const float d = (float)k*(1.0f/16000.0f) - xi;
    const float g = expf(ninv2s2*d*d);
    const float2 v = Xb[p];
    buf[p] = make_float2(v.x*g, v.y*g);
  }
  __syncthreads();
  fft_inv_g<16000>(buf, tid, NT);
  for (int n = tid; n < TN; n += NT){
    const float2 v = buf[n];
    buf[n] = make_float2(sqrtf(v.x*v.x + v.y*v.y) * (1.0f/16000.0f), 0.f);
  }
  __syncthreads();
  fft_fwd_g<16000>(buf, tid, NT);
  const int a = p1/12;
  const int lm = (a < 4) ? (8000 >> a) : ((a == 4) ? 1000 : 500);
  float2* Ub = U1h + (size_t)(b*84 + p1)*8000;
  for (int p = tid; p < TN; p += NT){
    const int k = pos2freq(p);
    if (k < lm) Ub[k] = buf[p];
  }
  lowpass_fold_store(buf, fb, tid, out + ((size_t)b*337 + 1 + p1)*125);
}

// ---------------- kernel 3: order 2, band-limited subsampled ----------------
// N = 125*2^c bins of U1h*psi2 fit the whole filter support; u2 computed on a
// stride-R grid (R=16000/N), |.|, then phi-conv with taps at multiples of R.
template<int N, int NTHREADS>
__global__ __launch_bounds__(NTHREADS) void k_order2_t(const float2* __restrict__ U1h,
                                                       float* __restrict__ out,
                                                       int j2){
  __shared__ float2 buf[N];
  __shared__ float part[640];
  const int tid = threadIdx.x;
  const int npath = 12*j2;             // valid p1 for this j2: p1 < 12*j2
  const int b  = blockIdx.x / npath;
  const int p1 = blockIdx.x % npath;
  const int a  = p1/12;
  const int r  = p1%12;
  const int q  = 12*(6*a - (a*(a-1))/2) + r*(6-a) + (j2 - a - 1);
  const float xi = 0.5f * exp2f(-(float)(j2+1));
  const float sg = 0.5f*xi;
  const float ninv2s2 = -1.0f/(2.0f*sg*sg);
  const float2* Zb = U1h + (size_t)(b*84 + p1)*8000;
  for (int k = tid; k < N; k += NTHREADS){
    const float d = (float)k*(1.0f/16000.0f) - xi;
    const float g = expf(ninv2s2*d*d);
    const float2 v = Zb[k];
    buf[freq2pos_g<N>(k)] = make_float2(v.x*g, v.y*g);
  }
  __syncthreads();
  fft_inv_g<N>(buf, tid, NTHREADS);
  for (int m = tid; m < N; m += NTHREADS){
    const float2 v = buf[m];
    buf[m].x = sqrtf(v.x*v.x + v.y*v.y)*(1.0f/16000.0f);
  }
  __syncthreads();
  constexpr int R = 16000/N;
  constexpr int CMAX = 320/R;
  constexpr int G = NTHREADS/125;      // taps split G-ways per output
  if (tid < 125*G){
    const int o = tid/G, g = tid%G;
    const int base = (o*128)/R;
    float acc = 0.f;
    for (int c = -CMAX + g; c <= CMAX; c += G){
      const float dd = (float)(c*R);
      const float h = 0.0078332134f * expf(-1.9276571e-4f*dd*dd);
      int idx = base - c;
      idx += (idx < 0) ? N : 0;
      idx -= (idx >= N) ? N : 0;
      acc += h*buf[idx].x;
    }
    part[tid] = acc;
  }
  __syncthreads();
  if (tid < 125){
    float s = 0.f;
#pragma unroll
    for (int gg=0; gg<G; ++gg) s += part[tid*G+gg];
    out[((size_t)b*337 + 85 + q)*125 + tid] = norm_val((float)R * s);
  }
}

extern "C" void kernel_launch(void* const* d_in, const int* in_sizes, int n_in,
                              void* d_out, int out_size, void* d_ws, size_t ws_size,
                              hipStream_t stream){
  (void)in_sizes; (void)n_in; (void)out_size; (void)ws_size;
  const float* x = (const float*)d_in[0];
  float* out = (float*)d_out;
  float2* Xrev = (float2*)d_ws;                                        // 1 MB
  float2* U1h  = (float2*)((char*)d_ws + (size_t)8*TN*sizeof(float2)); // 672*8000 cplx = 43 MB
  k_fftx  <<<8,    NT, 0, stream>>>(x, Xrev, out);
  k_order1<<<8*84, NT, 0, stream>>>(Xrev, U1h, out);
  k_order2_t<8000,640><<<8*12,  640, 0, stream>>>(U1h, out, 1);
  k_order2_t<4000,640><<<8*24,  640, 0, stream>>>(U1h, out, 2);
  k_order2_t<2000,512><<<8*36,  512, 0, stream>>>(U1h, out, 3);
  k_order2_t<1000,256><<<8*48,  256, 0, stream>>>(U1h, out, 4);
  k_order2_t<1000,256><<<8*60,  256, 0, stream>>>(U1h, out, 5);
  k_order2_t< 500,128><<<8*72,  128, 0, stream>>>(U1h, out, 6);
}

// Round 3
// 153.141 us; speedup vs baseline: 3.9039x; 2.1122x over previous
//
#include <hip/hip_runtime.h>

#define TN 16000
#define NT1 1024
#define NT2 640

constexpr int ilog2c(int x){ return (x<=1)?0:1+ilog2c(x/2); }

__device__ __forceinline__ float2 cmulf(float2 a, float2 b){
  return make_float2(a.x*b.x - a.y*b.y, a.x*b.y + a.y*b.x);
}

// Chain: radix 5,5,5 then radix-4s then final radix-2 (if odd # of 2s).
// Digit d of k (LSB-first in radix order) lands at stride N/(prod radices so far).
template<int N>
__device__ __forceinline__ int freq2pos(int k){
  constexpr int C = ilog2c(N/125);
  int u0 = k % 5; int t = k / 5;
  int u1 = t % 5; t /= 5;
  int u2 = t % 5; int q = t / 5;
  int p2 = 0;
  int L = 1 << C;
  if (L >= 4){ p2 += (q&3)*(L>>2); q >>= 2; L >>= 2; }
  if (L >= 4){ p2 += (q&3)*(L>>2); q >>= 2; L >>= 2; }
  if (L >= 4){ p2 += (q&3)*(L>>2); q >>= 2; L >>= 2; }
  if (L == 2){ p2 += (q&1); }
  return u0*(N/5) + u1*(N/25) + u2*(N/125) + p2;
}

template<bool INV>
__device__ __forceinline__ void dft5(const float2* y, float2* z){
  const float CR[5] = {1.f, 0.30901699437494742f, -0.80901699437494745f,
                       -0.80901699437494745f, 0.30901699437494742f};
  const float CI[5] = {0.f, -0.95105651629515357f, -0.58778525229247313f,
                       0.58778525229247313f, 0.95105651629515357f};
#pragma unroll
  for (int u=0;u<5;u++){
    float zr=0.f, zi=0.f;
#pragma unroll
    for (int t=0;t<5;t++){
      const int m = (t*u)%5;
      const float wr = CR[m];
      const float wi = INV ? -CI[m] : CI[m];
      zr += y[t].x*wr - y[t].y*wi;
      zi += y[t].x*wi + y[t].y*wr;
    }
    z[u] = make_float2(zr, zi);
  }
}

template<int N, int L, bool INV>
__device__ void stage5(float2* buf, int tid, int nt){
  const int M = L/5;
  for (int f = tid; f < N/5; f += nt){
    const int b = f / M;
    const int j = f - b*M;
    float2* p = buf + b*L + j;
    float2 v[5], w[5];
#pragma unroll
    for (int t=0;t<5;t++) v[t] = p[t*M];
    const float ang = (INV ? 6.28318530717958647692f : -6.28318530717958647692f)
                      * ((float)j / (float)L);
    float sn, cs; __sincosf(ang, &sn, &cs);
    const float2 w1 = make_float2(cs, sn);
    const float2 w2 = cmulf(w1,w1);
    const float2 w3 = cmulf(w2,w1);
    const float2 w4 = cmulf(w2,w2);
    if (INV){
      v[1]=cmulf(v[1],w1); v[2]=cmulf(v[2],w2); v[3]=cmulf(v[3],w3); v[4]=cmulf(v[4],w4);
      dft5<true>(v, w);
    } else {
      dft5<false>(v, w);
      w[1]=cmulf(w[1],w1); w[2]=cmulf(w[2],w2); w[3]=cmulf(w[3],w3); w[4]=cmulf(w[4],w4);
    }
#pragma unroll
    for (int u=0;u<5;u++) p[u*M] = w[u];
  }
}

template<int N, int L, bool INV>
__device__ void stage2(float2* buf, int tid, int nt){
  const int M = L/2;
  for (int f = tid; f < N/2; f += nt){
    const int b = f / M;
    const int j = f - b*M;
    float2* p = buf + b*L + j;
    float2 a0 = p[0], a1 = p[M];
    if (INV){
      if (M > 1){
        const float ang = 6.28318530717958647692f * ((float)j / (float)L);
        float sn, cs; __sincosf(ang, &sn, &cs);
        a1 = cmulf(a1, make_float2(cs, sn));
      }
      p[0] = make_float2(a0.x+a1.x, a0.y+a1.y);
      p[M] = make_float2(a0.x-a1.x, a0.y-a1.y);
    } else {
      float2 s = make_float2(a0.x+a1.x, a0.y+a1.y);
      float2 d = make_float2(a0.x-a1.x, a0.y-a1.y);
      if (M > 1){
        const float ang = -6.28318530717958647692f * ((float)j / (float)L);
        float sn, cs; __sincosf(ang, &sn, &cs);
        d = cmulf(d, make_float2(cs, sn));
      }
      p[0] = s; p[M] = d;
    }
  }
}

template<int N, int L, bool INV>
__device__ void stage4(float2* buf, int tid, int nt){
  const int M = L/4;
  for (int f = tid; f < N/4; f += nt){
    const int b = f / M;
    const int j = f - b*M;
    float2* p = buf + b*L + j;
    float2 a0 = p[0], a1 = p[M], a2 = p[2*M], a3 = p[3*M];
    float2 w1, w2, w3;
    if (M > 1){
      const float ang = (INV ? 6.28318530717958647692f : -6.28318530717958647692f)
                        * ((float)j / (float)L);
      float sn, cs; __sincosf(ang, &sn, &cs);
      w1 = make_float2(cs, sn);
      w2 = cmulf(w1,w1);
      w3 = cmulf(w2,w1);
      if (INV){ a1 = cmulf(a1,w1); a2 = cmulf(a2,w2); a3 = cmulf(a3,w3); }
    }
    const float2 s02 = make_float2(a0.x+a2.x, a0.y+a2.y);
    const float2 d02 = make_float2(a0.x-a2.x, a0.y-a2.y);
    const float2 s13 = make_float2(a1.x+a3.x, a1.y+a3.y);
    const float2 d13 = make_float2(a1.x-a3.x, a1.y-a3.y);
    float2 X0 = make_float2(s02.x+s13.x, s02.y+s13.y);
    float2 X2 = make_float2(s02.x-s13.x, s02.y-s13.y);
    float2 X1, X3;
    if (INV){
      X1 = make_float2(d02.x - d13.y, d02.y + d13.x);   // d02 + i*d13
      X3 = make_float2(d02.x + d13.y, d02.y - d13.x);   // d02 - i*d13
    } else {
      X1 = make_float2(d02.x + d13.y, d02.y - d13.x);   // d02 - i*d13
      X3 = make_float2(d02.x - d13.y, d02.y + d13.x);   // d02 + i*d13
    }
    if (!INV && M > 1){
      X1 = cmulf(X1,w1); X2 = cmulf(X2,w2); X3 = cmulf(X3,w3);
    }
    p[0] = X0; p[M] = X1; p[2*M] = X2; p[3*M] = X3;
  }
}

template<int N, int L>
__device__ __forceinline__ void fwd2chain(float2* buf, int tid, int nt){
  if constexpr (L >= 4){
    stage4<N, L, false>(buf, tid, nt); __syncthreads();
    fwd2chain<N, L/4>(buf, tid, nt);
  } else if constexpr (L == 2){
    stage2<N, 2, false>(buf, tid, nt); __syncthreads();
  }
}
template<int N, int L>
__device__ __forceinline__ void inv2chain(float2* buf, int tid, int nt){
  if constexpr (L <= N/125){
    if constexpr (L == 2){ stage2<N, 2, true>(buf, tid, nt); }
    else                 { stage4<N, L, true>(buf, tid, nt); }
    __syncthreads();
    inv2chain<N, L*4>(buf, tid, nt);
  }
}

template<int N>
__device__ void fft_fwd(float2* buf, int tid, int nt){
  stage5<N, N,    false>(buf, tid, nt); __syncthreads();
  stage5<N, N/5,  false>(buf, tid, nt); __syncthreads();
  stage5<N, N/25, false>(buf, tid, nt); __syncthreads();
  fwd2chain<N, N/125>(buf, tid, nt);
}
template<int N>
__device__ void fft_inv(float2* buf, int tid, int nt){
  constexpr int C = ilog2c(N/125);
  inv2chain<N, (C%2==1) ? 2 : 4>(buf, tid, nt);
  stage5<N, N/25, true>(buf, tid, nt); __syncthreads();
  stage5<N, N/5,  true>(buf, tid, nt); __syncthreads();
  stage5<N, N,    true>(buf, tid, nt); __syncthreads();
}

__device__ __forceinline__ float norm_val(float s){
  const float v = s;
  const float lt = log1pf(fabsf(v)*1.0e5f)*1.0e-5f;
  return 0.7f*v + 0.3f*copysignf(lt, v);
}

// ---------------- kernel 1: window + S0 (time conv) + FFT(x) -> Xnat ----------------
__global__ __launch_bounds__(NT1) void k_fftx(const float* __restrict__ x,
                                              float2* __restrict__ Xnat,
                                              float* __restrict__ out){
  __shared__ float2 buf[TN];
  __shared__ float part[NT1];
  const int tid = threadIdx.x;
  const int b = blockIdx.x;
  const float* xb = x + b*TN;
  for (int n = tid; n < TN; n += NT1){
    float c = __cosf((float)n * (6.28318530717958647692f/16000.0f));
    float wn = 0.08f + 0.46f*(1.0f - c);
    buf[n] = make_float2(xb[n]*wn, 0.f);
  }
  __syncthreads();
  {
    constexpr int G = NT1/125;   // 8
    const int o = tid/G, g = tid%G;
    if (o < 125){
      const int base = o*128;
      float acc = 0.f;
      for (int c = -320 + g; c <= 320; c += G){
        const float dd = (float)c;
        const float h = 0.0078332134f * __expf(-1.9276571e-4f*dd*dd);
        int idx = base - c;
        idx += (idx < 0) ? TN : 0;
        idx -= (idx >= TN) ? TN : 0;
        acc += h*buf[idx].x;
      }
      part[tid] = acc;
    }
    __syncthreads();
    if (tid < 125){
      float s = 0.f;
#pragma unroll
      for (int gg=0; gg<G; ++gg) s += part[tid*G+gg];
      out[(size_t)b*337*125 + tid] = norm_val(s);
    }
  }
  __syncthreads();
  fft_fwd<TN>(buf, tid, NT1);
  float2* Xb = Xnat + (size_t)b*TN;
  for (int k = tid; k < TN; k += NT1) Xb[k] = buf[freq2pos<TN>(k)];
}

// ---------------- kernel 2: order 1, per-octave band-limited ----------------
template<int N1>
__device__ void order1_body(const float2* __restrict__ Xnat,
                            float2* __restrict__ U1h,
                            float* __restrict__ out,
                            int b, int p1, int tid,
                            float2* buf, float* part){
  constexpr int A = ilog2c(TN/N1);     // octave
  constexpr int R1 = TN/N1;
  const float xi = 0.5f * exp2f(-(float)(p1+1) * (1.0f/12.0f));
  const float sg = xi * 0.11892618871859045f;
  const float ninv2s2 = -1.0f/(2.0f*sg*sg);
  const float2* Xb = Xnat + (size_t)b*TN;
  for (int k = tid; k < N1; k += NT1){
    const float d = (float)k*(1.0f/16000.0f) - xi;
    const float g = __expf(ninv2s2*d*d);
    const float2 v = Xb[k];
    buf[freq2pos<N1>(k)] = make_float2(v.x*g, v.y*g);
  }
  __syncthreads();
  fft_inv<N1>(buf, tid, NT1);
  for (int n = tid; n < N1; n += NT1){
    const float2 v = buf[n];
    buf[n] = make_float2(sqrtf(v.x*v.x + v.y*v.y) * (1.0f/16000.0f), 0.f);
  }
  __syncthreads();
  // S1 via time-domain phi conv on the subsampled grid
  {
    constexpr int CMAX = 320/R1;
    constexpr int G = NT1/125;   // 8
    const int o = tid/G, g = tid%G;
    if (o < 125){
      const int base = (o*128)/R1;
      float acc = 0.f;
      for (int c = -CMAX + g; c <= CMAX; c += G){
        const float dd = (float)(c*R1);
        const float h = 0.0078332134f * __expf(-1.9276571e-4f*dd*dd);
        int idx = base - c;
        idx += (idx < 0) ? N1 : 0;
        idx -= (idx >= N1) ? N1 : 0;
        acc += h*buf[idx].x;
      }
      part[tid] = acc;
    }
    __syncthreads();
    if (tid < 125){
      float s = 0.f;
#pragma unroll
      for (int gg=0; gg<G; ++gg) s += part[tid*G+gg];
      out[((size_t)b*337 + 1 + p1)*125 + tid] = norm_val((float)R1 * s);
    }
  }
  if constexpr (A <= 5){
    __syncthreads();
    fft_fwd<N1>(buf, tid, NT1);
    constexpr int LM = (A <= 3) ? N1/2 : N1;
    float2* Ub = U1h + (size_t)(b*84 + p1)*8000;
    for (int k = tid; k < LM; k += NT1){
      const float2 v = buf[freq2pos<N1>(k)];
      Ub[k] = make_float2((float)R1*v.x, (float)R1*v.y);
    }
  }
}

__global__ __launch_bounds__(NT1) void k_order1(const float2* __restrict__ Xnat,
                                                float2* __restrict__ U1h,
                                                float* __restrict__ out){
  __shared__ float2 buf[TN];
  __shared__ float part[NT1];
  const int tid = threadIdx.x;
  const int a = blockIdx.x / 96;       // octaves in increasing order: big first
  const int r = blockIdx.x % 96;
  const int b = r / 12;
  const int p1 = a*12 + (r % 12);
  switch (a){
    case 0: order1_body<16000>(Xnat,U1h,out,b,p1,tid,buf,part); break;
    case 1: order1_body< 8000>(Xnat,U1h,out,b,p1,tid,buf,part); break;
    case 2: order1_body< 4000>(Xnat,U1h,out,b,p1,tid,buf,part); break;
    case 3: order1_body< 2000>(Xnat,U1h,out,b,p1,tid,buf,part); break;
    case 4: order1_body< 1000>(Xnat,U1h,out,b,p1,tid,buf,part); break;
    case 5: order1_body<  500>(Xnat,U1h,out,b,p1,tid,buf,part); break;
    default: order1_body< 250>(Xnat,U1h,out,b,p1,tid,buf,part); break;
  }
}

// ---------------- kernel 3: order 2 fused ----------------
template<int N>
__device__ void order2_body(const float2* __restrict__ U1h,
                            float* __restrict__ out,
                            int b, int p1, int j2, int q, int tid,
                            float2* buf, float* part){
  const float xi = 0.5f * exp2f(-(float)(j2+1));
  const float sg = 0.5f*xi;
  const float ninv2s2 = -1.0f/(2.0f*sg*sg);
  const float2* Zb = U1h + (size_t)(b*84 + p1)*8000;
  for (int k = tid; k < N; k += NT2){
    const float d = (float)k*(1.0f/16000.0f) - xi;
    const float g = __expf(ninv2s2*d*d);
    const float2 v = Zb[k];
    buf[freq2pos<N>(k)] = make_float2(v.x*g, v.y*g);
  }
  __syncthreads();
  fft_inv<N>(buf, tid, NT2);
  for (int m = tid; m < N; m += NT2){
    const float2 v = buf[m];
    buf[m].x = sqrtf(v.x*v.x + v.y*v.y)*(1.0f/16000.0f);
  }
  __syncthreads();
  constexpr int R = TN/N;
  constexpr int CMAX = 320/R;
  constexpr int G = NT2/125;   // 5
  if (tid < 125*G){
    const int o = tid/G, g = tid%G;
    const int base = (o*128)/R;
    float acc = 0.f;
    for (int c = -CMAX + g; c <= CMAX; c += G){
      const float dd = (float)(c*R);
      const float h = 0.0078332134f * __expf(-1.9276571e-4f*dd*dd);
      int idx = base - c;
      idx += (idx < 0) ? N : 0;
      idx -= (idx >= N) ? N : 0;
      acc += h*buf[idx].x;
    }
    part[tid] = acc;
  }
  __syncthreads();
  if (tid < 125){
    float s = 0.f;
#pragma unroll
    for (int gg=0; gg<G; ++gg) s += part[tid*G+gg];
    out[((size_t)b*337 + 85 + q)*125 + tid] = norm_val((float)R * s);
  }
}

__global__ __launch_bounds__(NT2) void k_order2(const float2* __restrict__ U1h,
                                                float* __restrict__ out){
  __shared__ float2 buf[8000];
  __shared__ float part[NT2];
  const int tid = threadIdx.x;
  int id = blockIdx.x;
  int j2;
  if      (id <   96){ j2 = 1; }
  else if (id <  288){ j2 = 2; id -=   96; }
  else if (id <  576){ j2 = 3; id -=  288; }
  else if (id <  960){ j2 = 4; id -=  576; }
  else if (id < 1440){ j2 = 5; id -=  960; }
  else               { j2 = 6; id -= 1440; }
  const int npath = 12*j2;
  const int b  = id / npath;
  const int p1 = id % npath;
  const int a = p1/12, r = p1%12;
  const int q = 12*(6*a - (a*(a-1))/2) + r*(6-a) + (j2 - a - 1);
  switch (j2){
    case 1: order2_body<8000>(U1h,out,b,p1,1,q,tid,buf,part); break;
    case 2: order2_body<4000>(U1h,out,b,p1,2,q,tid,buf,part); break;
    case 3: order2_body<2000>(U1h,out,b,p1,3,q,tid,buf,part); break;
    case 4: order2_body<1000>(U1h,out,b,p1,4,q,tid,buf,part); break;
    case 5: order2_body<1000>(U1h,out,b,p1,5,q,tid,buf,part); break;
    default: order2_body<500>(U1h,out,b,p1,6,q,tid,buf,part); break;
  }
}

extern "C" void kernel_launch(void* const* d_in, const int* in_sizes, int n_in,
                              void* d_out, int out_size, void* d_ws, size_t ws_size,
                              hipStream_t stream){
  (void)in_sizes; (void)n_in; (void)out_size; (void)ws_size;
  const float* x = (const float*)d_in[0];
  float* out = (float*)d_out;
  float2* Xnat = (float2*)d_ws;                                        // 1 MB
  float2* U1h  = (float2*)((char*)d_ws + (size_t)8*TN*sizeof(float2)); // 43 MB
  k_fftx  <<<8,    NT1, 0, stream>>>(x, Xnat, out);
  k_order1<<<672,  NT1, 0, stream>>>(Xnat, U1h, out);
  k_order2<<<2016, NT2, 0, stream>>>(U1h, out);
}